// Round 7
// baseline (181.818 us; speedup 1.0000x reference)
//
#include <hip/hip_runtime.h>
#include <math.h>

namespace {

constexpr int NUM_NEG   = 8;
constexpr int BROWS     = 262144;
constexpr int NUM_ITEMS_C = 20000;
constexpr int M_IMP_C   = 2000;
constexpr float MARGIN1 = 0.1f;
constexpr float MARGIN2 = 0.1f;
constexpr float TAU     = 0.2f;
constexpr float EPS1    = 1e-7f;
constexpr float MAXNORM = 1.0f - 1e-5f;

// phase-serial fusion: every block does [cls -> cl -> rank]
constexpr int NBLK   = 2048;
constexpr int NWAVES = NBLK * 4;   // 8192

__device__ __forceinline__ float wredsum(float v) {
    v += __shfl_xor(v, 1);  v += __shfl_xor(v, 2);  v += __shfl_xor(v, 4);
    v += __shfl_xor(v, 8);  v += __shfl_xor(v, 16); v += __shfl_xor(v, 32);
    return v;
}
__device__ __forceinline__ float wredmax(float v) {
    v = fmaxf(v, __shfl_xor(v, 1));  v = fmaxf(v, __shfl_xor(v, 2));
    v = fmaxf(v, __shfl_xor(v, 4));  v = fmaxf(v, __shfl_xor(v, 8));
    v = fmaxf(v, __shfl_xor(v, 16)); v = fmaxf(v, __shfl_xor(v, 32));
    return v;
}
__device__ __forceinline__ float bcast(float v, int l) {
    return __int_as_float(__builtin_amdgcn_readlane(__float_as_int(v), l));
}
__device__ __forceinline__ float fsq(float x)  { return __builtin_amdgcn_sqrtf(x); }
__device__ __forceinline__ float frc(float x)  { return __builtin_amdgcn_rcpf(x); }
__device__ __forceinline__ float artanh_fast(float n) {
    n = fminf(n, MAXNORM);
    return 0.5f * __logf((1.f + n) * frc(1.f - n));
}
__device__ __forceinline__ float acosh_fast(float z) {
    z = fmaxf(z, 1.0f + EPS1);
    return __logf(z + fsq(fmaf(z, z, -1.0f)));
}
__device__ __forceinline__ float tanh_fast(float x) {
    const float t = __expf(2.f * x);
    return (t - 1.f) * frc(t + 1.f);
}
__device__ __forceinline__ float dot4(const float4& a, const float4& b) {
    return a.x * b.x + a.y * b.y + a.z * b.z + a.w * b.w;
}

__global__ __launch_bounds__(256) void fused_kernel(
        const float* __restrict__ emb,  const int* __restrict__ tri,
        const float* __restrict__ vtg,  const float* __restrict__ etag,
        const float* __restrict__ linw, const float* __restrict__ linb,
        const float* __restrict__ tw,   const int* __restrict__ labels,
        const int* __restrict__ imp,    float* __restrict__ part) {
    __shared__ float SA[64 * 65];   // W^T -> BT -> TT (pitch 65)
    __shared__ float s64[64];
    __shared__ float red4[4];
    const int tid  = threadIdx.x;
    const int lane = tid & 63, wid = tid >> 6;
    const int b    = blockIdx.x;
    const int gw   = b * 4 + wid;          // global wave id, 0..8191
    float wacc = 0.f;                      // wave-uniform running partial

    // ================= cls phase (<=3 items per wave) ======================
    for (int i = tid; i < 4096; i += 256) {
        const int r = i >> 6, d = i & 63;
        SA[d * 65 + r] = linw[i];          // W transposed
    }
    __syncthreads();
    const float bias = linb[lane];
    const float y2b  = wredsum(bias * bias);

    auto phase1 = [&](int i) -> float {    // log-mapped vector a (named regs)
        if (i >= NUM_ITEMS_C) return 0.f;  // wave-uniform guard
        float x  = vtg[(long)i * 64 + lane];
        float x2 = wredsum(x * x);
        float xn = fsq(fmaxf(x2, 1e-15f));
        if (xn > MAXNORM) {                // ball_projx (wave-uniform)
            x *= MAXNORM * frc(xn);
            x2 = wredsum(x * x);
            xn = fsq(fmaxf(x2, 1e-15f));
        }
        float m0 = 0.f, m1 = 0.f, m2 = 0.f, m3 = 0.f;
        #pragma unroll
        for (int d = 0; d < 64; d += 4) {
            m0 = fmaf(bcast(x, d),     SA[(d)     * 65 + lane], m0);
            m1 = fmaf(bcast(x, d + 1), SA[(d + 1) * 65 + lane], m1);
            m2 = fmaf(bcast(x, d + 2), SA[(d + 2) * 65 + lane], m2);
            m3 = fmaf(bcast(x, d + 3), SA[(d + 3) * 65 + lane], m3);
        }
        const float mx  = (m0 + m1) + (m2 + m3);
        const float mn  = fsq(fmaxf(wredsum(mx * mx), 1e-15f));
        const float g   = tanh_fast(mn * frc(xn) * artanh_fast(xn));
        const float h1  = g * frc(mn) * mx;
        const float x2h = wredsum(h1 * h1);
        const float xy  = wredsum(h1 * bias);
        const float A   = 1.f + 2.f * xy + y2b;
        const float Bc  = 1.f - x2h;
        const float den = fmaxf(1.f + 2.f * xy + x2h * y2b, 1e-15f);
        float hh = (A * h1 + Bc * bias) * frc(den);
        float hn = fsq(fmaxf(wredsum(hh * hh), 1e-15f));
        if (hn > MAXNORM) {                // ball_projx
            hh *= MAXNORM * frc(hn);
            hn = fsq(fmaxf(wredsum(hh * hh), 1e-15f));
        }
        return artanh_fast(hn) * frc(hn) * hh;   // ball_logmap0
    };
    const float a0 = phase1(gw);
    const float a1 = phase1(gw + NWAVES);
    const float a2 = phase1(gw + 2 * NWAVES);
    __syncthreads();
    // rebuild LDS: BT = logmap0(emb_tag)^T, s64 = ||bt||^2
    {
        const int j = tid >> 2, p = tid & 3;
        float e[16]; float s2 = 0.f;
        #pragma unroll
        for (int m = 0; m < 16; ++m) { e[m] = etag[j * 64 + p * 16 + m]; s2 += e[m] * e[m]; }
        s2 += __shfl_xor(s2, 1); s2 += __shfl_xor(s2, 2);
        const float n  = fsq(fmaxf(s2, 1e-15f));
        const float sc = artanh_fast(n) * frc(n);
        #pragma unroll
        for (int m = 0; m < 16; ++m) SA[(p * 16 + m) * 65 + j] = sc * e[m];
        if (p == 0) s64[j] = sc * sc * s2;
    }
    __syncthreads();
    const float twl = tw[lane];
    const float b2l = s64[lane];
    auto phase2 = [&](float a, int i) -> float {
        if (i >= NUM_ITEMS_C) return 0.f;
        const float a2v = wredsum(a * a);
        float d0 = 0.f, d1 = 0.f, d2 = 0.f, d3 = 0.f;
        #pragma unroll
        for (int d = 0; d < 64; d += 4) {
            d0 = fmaf(bcast(a, d),     SA[(d)     * 65 + lane], d0);
            d1 = fmaf(bcast(a, d + 1), SA[(d + 1) * 65 + lane], d1);
            d2 = fmaf(bcast(a, d + 2), SA[(d + 2) * 65 + lane], d2);
            d3 = fmaf(bcast(a, d + 3), SA[(d + 3) * 65 + lane], d3);
        }
        const float dot  = (d0 + d1) + (d2 + d3);
        const float dist = fsq(fmaxf(a2v + b2l - 2.f * dot, 1e-12f));
        const float logp = __logf(dist) - twl;
        float s0 = 0.f, s1 = 0.f, s2 = 0.f, s3 = 0.f;
        #pragma unroll
        for (int k = 0; k < 64; k += 4) {
            s0 += fmaxf(logp - bcast(logp, k)     + MARGIN1, 0.f);
            s1 += fmaxf(logp - bcast(logp, k + 1) + MARGIN1, 0.f);
            s2 += fmaxf(logp - bcast(logp, k + 2) + MARGIN1, 0.f);
            s3 += fmaxf(logp - bcast(logp, k + 3) + MARGIN1, 0.f);
        }
        const float hs = (s0 + s1) + (s2 + s3);
        const float c  = (labels[(long)i * 64 + lane] > 0) ? hs : 0.f;
        return wredsum(c);
    };
    wacc += phase2(a0, gw);
    wacc += phase2(a1, gw + NWAVES);
    wacc += phase2(a2, gw + 2 * NWAVES);
    __syncthreads();

    // ================= cl phase (<=1 pair per wave) ========================
    {   // rebuild LDS: TT = emb_tag^T (raw), s64 = ||tag||^2
        const int j = tid >> 2, p = tid & 3;
        float s2 = 0.f;
        #pragma unroll
        for (int m = 0; m < 16; ++m) {
            const float e = etag[j * 64 + p * 16 + m];
            s2 += e * e;
            SA[(p * 16 + m) * 65 + j] = e;
        }
        s2 += __shfl_xor(s2, 1); s2 += __shfl_xor(s2, 2);
        if (p == 0) s64[j] = s2;
    }
    __syncthreads();
    if (gw < M_IMP_C) {
        const int ai = imp[gw * 2];
        const int bi = imp[gw * 2 + 1];
        const float y2l = s64[lane];
        const float x2  = s64[ai];
        float c0 = 0.f, c1 = 0.f, c2 = 0.f, c3 = 0.f;
        #pragma unroll
        for (int d = 0; d < 64; d += 4) {
            c0 = fmaf(SA[(d)     * 65 + ai], SA[(d)     * 65 + lane], c0);
            c1 = fmaf(SA[(d + 1) * 65 + ai], SA[(d + 1) * 65 + lane], c1);
            c2 = fmaf(SA[(d + 2) * 65 + ai], SA[(d + 2) * 65 + lane], c2);
            c3 = fmaf(SA[(d + 3) * 65 + ai], SA[(d + 3) * 65 + lane], c3);
        }
        const float c   = (c0 + c1) + (c2 + c3);
        const float A   = 1.f - 2.f * c + y2l;
        const float Bc  = 1.f - x2;
        const float nn  = A * A * x2 - 2.f * A * Bc * c + Bc * Bc * y2l;
        const float den = fmaxf(1.f - 2.f * c + x2 * y2l, 1e-15f);
        float n = fsq(fmaxf(nn * frc(den * den), 1e-15f));
        n = fminf(n, MAXNORM);
        const float dd = __logf((1.f + n) * frc(1.f - n));   // 2*artanh(n)
        float dist = dd * dd;
        if (lane == ai) dist = 0.f;        // self-distance: ref < 1e-9 -> masked
        const float logit = (dist > 1e-9f) ? (-dist * (1.f / TAU)) : -1e30f;
        const float dp = bcast(dist, bi);
        const float lp = bcast(logit, bi);
        const float m  = wredmax(logit);
        const float se = wredsum(__expf(logit - m)) + __expf(lp - m);
        wacc += m + __logf(se) + dp * (1.f / TAU);
    }

    // ====== rank phase: lane = (row, neg k); 8 rows/wave; shuffle-free =====
    {
        const int k  = lane & 7;           // neg index
        const int rw = lane >> 3;          // row within wave
        float racc = 0.f;                  // per-lane: hinge term of (row, k)
        // rows per sweep = NWAVES*8 = 65536; BROWS/65536 = 4 iterations exact
        for (int row = gw * 8 + rw; row < BROWS; row += NWAVES * 8) {
            const int* t = tri + (long)row * 10;
            const int2 t01 = *reinterpret_cast<const int2*>(t);
            const int  ni  = t[2 + k];
            const float* ub = emb + (long)t01.x * 64;
            const float* pb = emb + (long)t01.y * 64;
            const float* nb = emb + (long)ni   * 64;
            float dpos = 0.f, dneg = 0.f;
            float u0 = 0.f, p0 = 0.f, n0 = 0.f;
            #pragma unroll
            for (int c = 0; c < 4; ++c) {   // 4 chunks x 16 floats
                const float4* uc = reinterpret_cast<const float4*>(ub + c * 16);
                const float4* pc = reinterpret_cast<const float4*>(pb + c * 16);
                const float4* nc = reinterpret_cast<const float4*>(nb + c * 16);
                const float4 ua = uc[0], ubv = uc[1], uw = uc[2], ux = uc[3];
                const float4 pa = pc[0], pbv = pc[1], pw = pc[2], px = pc[3];
                const float4 na = nc[0], nbv = nc[1], nw = nc[2], nx = nc[3];
                if (c == 0) { u0 = ua.x; p0 = pa.x; n0 = na.x; }
                dpos += (dot4(ua, pa) + dot4(ubv, pbv)) + (dot4(uw, pw) + dot4(ux, px));
                dneg += (dot4(ua, na) + dot4(ubv, nbv)) + (dot4(uw, nw) + dot4(ux, nx));
            }
            // lorentz inner = full_dot - 2*x0*y0
            const float lp_ = dpos - 2.f * u0 * p0;
            const float ln_ = dneg - 2.f * u0 * n0;
            const float dp_ = acosh_fast(-lp_);
            const float dn_ = acosh_fast(-ln_);
            const float alpha = acosh_fast(u0);
            racc += fmaxf((dp_ * dp_ - dn_ * dn_ + MARGIN2) * alpha, 0.f);
        }
        wacc += wredsum(racc);             // sums all (row, k) hinge terms
    }

    if (lane == 0) red4[wid] = wacc;
    __syncthreads();
    if (tid == 0) part[b] = red4[0] + red4[1] + red4[2] + red4[3];
}

__global__ __launch_bounds__(256) void final_reduce(
        const float* __restrict__ parts, int n, float* __restrict__ out) {
    __shared__ double red[256];
    double s = 0.0;
    for (int i = threadIdx.x; i < n; i += 256) s += (double)parts[i];
    red[threadIdx.x] = s;
    __syncthreads();
    for (int off = 128; off > 0; off >>= 1) {
        if (threadIdx.x < off) red[threadIdx.x] += red[threadIdx.x + off];
        __syncthreads();
    }
    if (threadIdx.x == 0) out[0] = (float)red[0];
}

} // namespace

extern "C" void kernel_launch(void* const* d_in, const int* in_sizes, int n_in,
                              void* d_out, int out_size, void* d_ws, size_t ws_size,
                              hipStream_t stream) {
    const float* emb    = (const float*)d_in[0];
    const float* vtg    = (const float*)d_in[1];
    const float* etag   = (const float*)d_in[2];
    const float* linw   = (const float*)d_in[3];
    const float* linb   = (const float*)d_in[4];
    const float* tw     = (const float*)d_in[5];
    const int*   tri    = (const int*)d_in[6];
    const int*   labels = (const int*)d_in[7];
    const int*   imp    = (const int*)d_in[8];
    float* parts = (float*)d_ws;

    fused_kernel<<<NBLK, 256, 0, stream>>>(emb, tri, vtg, etag, linw, linb,
                                           tw, labels, imp, parts);
    final_reduce<<<1, 256, 0, stream>>>(parts, NBLK, (float*)d_out);
}

// Round 8
// 95.807 us; speedup vs baseline: 1.8978x; 1.8978x over previous
//
#include <hip/hip_runtime.h>
#include <math.h>

namespace {

constexpr int NUM_NEG   = 8;
constexpr int BROWS     = 262144;
constexpr int NUM_ITEMS_C = 20000;
constexpr int M_IMP_C   = 2000;
constexpr float MARGIN1 = 0.1f;
constexpr float MARGIN2 = 0.1f;
constexpr float TAU     = 0.2f;
constexpr float EPS1    = 1e-7f;
constexpr float MAXNORM = 1.0f - 1e-5f;

// phase-serial fusion: every block does [cls -> cl -> rank]
constexpr int NBLK   = 2048;
constexpr int NWAVES = NBLK * 4;   // 8192

__device__ __forceinline__ float wredsum(float v) {
    v += __shfl_xor(v, 1);  v += __shfl_xor(v, 2);  v += __shfl_xor(v, 4);
    v += __shfl_xor(v, 8);  v += __shfl_xor(v, 16); v += __shfl_xor(v, 32);
    return v;
}
__device__ __forceinline__ float wredmax(float v) {
    v = fmaxf(v, __shfl_xor(v, 1));  v = fmaxf(v, __shfl_xor(v, 2));
    v = fmaxf(v, __shfl_xor(v, 4));  v = fmaxf(v, __shfl_xor(v, 8));
    v = fmaxf(v, __shfl_xor(v, 16)); v = fmaxf(v, __shfl_xor(v, 32));
    return v;
}
__device__ __forceinline__ float bcast(float v, int l) {
    return __int_as_float(__builtin_amdgcn_readlane(__float_as_int(v), l));
}
__device__ __forceinline__ float fsq(float x)  { return __builtin_amdgcn_sqrtf(x); }
__device__ __forceinline__ float frc(float x)  { return __builtin_amdgcn_rcpf(x); }
__device__ __forceinline__ float artanh_fast(float n) {
    n = fminf(n, MAXNORM);
    return 0.5f * __logf((1.f + n) * frc(1.f - n));
}
__device__ __forceinline__ float acosh_fast(float z) {
    z = fmaxf(z, 1.0f + EPS1);
    return __logf(z + fsq(fmaf(z, z, -1.0f)));
}
__device__ __forceinline__ float tanh_fast(float x) {
    const float t = __expf(2.f * x);
    return (t - 1.f) * frc(t + 1.f);
}
__device__ __forceinline__ float dot4(const float4& a, const float4& b) {
    return (a.x * b.x + a.y * b.y) + (a.z * b.z + a.w * b.w);
}

__global__ __launch_bounds__(256) void fused_kernel(
        const float* __restrict__ emb,  const int* __restrict__ tri,
        const float* __restrict__ vtg,  const float* __restrict__ etag,
        const float* __restrict__ linw, const float* __restrict__ linb,
        const float* __restrict__ tw,   const int* __restrict__ labels,
        const int* __restrict__ imp,    float* __restrict__ part) {
    __shared__ float SA[64 * 65];   // W^T -> BT -> TT (pitch 65)
    __shared__ float s64[64];
    __shared__ float red4[4];
    const int tid  = threadIdx.x;
    const int lane = tid & 63, wid = tid >> 6;
    const int b    = blockIdx.x;
    const int gw   = b * 4 + wid;          // global wave id, 0..8191
    float wacc = 0.f;

    // ================= cls phase: 3 items per wave, batched ================
    for (int i = tid; i < 4096; i += 256) {
        const int r = i >> 6, d = i & 63;
        SA[d * 65 + r] = linw[i];          // W transposed, pitch 65
    }
    __syncthreads();
    const float bias = linb[lane];
    const float y2b  = wredsum(bias * bias);
    const int i0 = gw, i1 = gw + NWAVES, i2 = gw + 2 * NWAVES;
    const bool v1 = (i1 < NUM_ITEMS_C), v2 = (i2 < NUM_ITEMS_C);

    float xv0 = vtg[(long)i0 * 64 + lane];                 // i0 < 8192 always valid
    float xv1 = v1 ? vtg[(long)i1 * 64 + lane] : 0.f;
    float xv2 = v2 ? vtg[(long)i2 * 64 + lane] : 0.f;

    auto prep = [&](float& x) -> float {   // ball_projx; returns xn
        float n2 = wredsum(x * x);
        float n  = fsq(fmaxf(n2, 1e-15f));
        if (n > MAXNORM) {                 // wave-uniform
            x *= MAXNORM * frc(n);
            n2 = wredsum(x * x);
            n  = fsq(fmaxf(n2, 1e-15f));
        }
        return n;
    };
    const float xn0 = prep(xv0);
    const float xn1 = prep(xv1);
    const float xn2 = prep(xv2);

    // batched mobius_matvec inner product: share the W ds_read across items
    float ma0 = 0.f, ma1 = 0.f, mb0 = 0.f, mb1 = 0.f, mc0 = 0.f, mc1 = 0.f;
    #pragma unroll
    for (int d = 0; d < 64; d += 2) {
        const float w0 = SA[(d)     * 65 + lane];
        const float w1 = SA[(d + 1) * 65 + lane];
        ma0 = fmaf(bcast(xv0, d), w0, ma0);  ma1 = fmaf(bcast(xv0, d + 1), w1, ma1);
        mb0 = fmaf(bcast(xv1, d), w0, mb0);  mb1 = fmaf(bcast(xv1, d + 1), w1, mb1);
        mc0 = fmaf(bcast(xv2, d), w0, mc0);  mc1 = fmaf(bcast(xv2, d + 1), w1, mc1);
    }
    auto tail = [&](float mx, float xn) -> float {  // -> log-mapped a (lane d)
        const float mn  = fsq(fmaxf(wredsum(mx * mx), 1e-15f));
        const float g   = tanh_fast(mn * frc(xn) * artanh_fast(xn));
        const float h1  = g * frc(mn) * mx;
        const float x2h = wredsum(h1 * h1);
        const float xy  = wredsum(h1 * bias);
        const float A   = 1.f + 2.f * xy + y2b;
        const float Bc  = 1.f - x2h;
        const float den = fmaxf(1.f + 2.f * xy + x2h * y2b, 1e-15f);
        float hh = (A * h1 + Bc * bias) * frc(den);
        float hn = fsq(fmaxf(wredsum(hh * hh), 1e-15f));
        if (hn > MAXNORM) {                // ball_projx (wave-uniform)
            hh *= MAXNORM * frc(hn);
            hn = fsq(fmaxf(wredsum(hh * hh), 1e-15f));
        }
        return artanh_fast(hn) * frc(hn) * hh;     // ball_logmap0
    };
    const float av0 = tail(ma0 + ma1, xn0);
    const float av1 = tail(mb0 + mb1, xn1);
    const float av2 = tail(mc0 + mc1, xn2);
    __syncthreads();
    // rebuild LDS: BT = logmap0(emb_tag)^T, s64 = ||bt||^2
    {
        const int j = tid >> 2, p = tid & 3;
        float e[16]; float s2 = 0.f;
        #pragma unroll
        for (int m = 0; m < 16; ++m) { e[m] = etag[j * 64 + p * 16 + m]; s2 += e[m] * e[m]; }
        s2 += __shfl_xor(s2, 1); s2 += __shfl_xor(s2, 2);
        const float n  = fsq(fmaxf(s2, 1e-15f));
        const float sc = artanh_fast(n) * frc(n);
        #pragma unroll
        for (int m = 0; m < 16; ++m) SA[(p * 16 + m) * 65 + j] = sc * e[m];
        if (p == 0) s64[j] = sc * sc * s2;
    }
    __syncthreads();
    const float twl = tw[lane];
    const float b2l = s64[lane];
    // batched tag-distance dot: share the BT ds_read across items
    float da0 = 0.f, da1 = 0.f, db0 = 0.f, db1 = 0.f, dc0 = 0.f, dc1 = 0.f;
    #pragma unroll
    for (int d = 0; d < 64; d += 2) {
        const float w0 = SA[(d)     * 65 + lane];
        const float w1 = SA[(d + 1) * 65 + lane];
        da0 = fmaf(bcast(av0, d), w0, da0);  da1 = fmaf(bcast(av0, d + 1), w1, da1);
        db0 = fmaf(bcast(av1, d), w0, db0);  db1 = fmaf(bcast(av1, d + 1), w1, db1);
        dc0 = fmaf(bcast(av2, d), w0, dc0);  dc1 = fmaf(bcast(av2, d + 1), w1, dc1);
    }
    auto hinge = [&](float a, float dot, int i) -> float {
        const float a2v  = wredsum(a * a);
        const float dist = fsq(fmaxf(a2v + b2l - 2.f * dot, 1e-12f));
        const float logp = __logf(dist) - twl;
        float s0 = 0.f, s1 = 0.f, s2 = 0.f, s3 = 0.f;
        #pragma unroll
        for (int k = 0; k < 64; k += 4) {
            s0 += fmaxf(logp - bcast(logp, k)     + MARGIN1, 0.f);
            s1 += fmaxf(logp - bcast(logp, k + 1) + MARGIN1, 0.f);
            s2 += fmaxf(logp - bcast(logp, k + 2) + MARGIN1, 0.f);
            s3 += fmaxf(logp - bcast(logp, k + 3) + MARGIN1, 0.f);
        }
        const float hs = (s0 + s1) + (s2 + s3);
        const float c  = (labels[(long)i * 64 + lane] > 0) ? hs : 0.f;
        return wredsum(c);
    };
    wacc += hinge(av0, da0 + da1, i0);
    if (v1) wacc += hinge(av1, db0 + db1, i1);
    if (v2) wacc += hinge(av2, dc0 + dc1, i2);
    __syncthreads();

    // ================= cl phase (<=1 pair per wave) ========================
    {   // rebuild LDS: TT = emb_tag^T (raw), s64 = ||tag||^2
        const int j = tid >> 2, p = tid & 3;
        float s2 = 0.f;
        #pragma unroll
        for (int m = 0; m < 16; ++m) {
            const float e = etag[j * 64 + p * 16 + m];
            s2 += e * e;
            SA[(p * 16 + m) * 65 + j] = e;
        }
        s2 += __shfl_xor(s2, 1); s2 += __shfl_xor(s2, 2);
        if (p == 0) s64[j] = s2;
    }
    __syncthreads();
    if (gw < M_IMP_C) {
        const int ai = imp[gw * 2];
        const int bi = imp[gw * 2 + 1];
        const float y2l = s64[lane];
        const float x2  = s64[ai];
        float c0 = 0.f, c1 = 0.f, c2 = 0.f, c3 = 0.f;
        #pragma unroll
        for (int d = 0; d < 64; d += 4) {
            c0 = fmaf(SA[(d)     * 65 + ai], SA[(d)     * 65 + lane], c0);
            c1 = fmaf(SA[(d + 1) * 65 + ai], SA[(d + 1) * 65 + lane], c1);
            c2 = fmaf(SA[(d + 2) * 65 + ai], SA[(d + 2) * 65 + lane], c2);
            c3 = fmaf(SA[(d + 3) * 65 + ai], SA[(d + 3) * 65 + lane], c3);
        }
        const float c   = (c0 + c1) + (c2 + c3);
        const float A   = 1.f - 2.f * c + y2l;
        const float Bc  = 1.f - x2;
        const float nn  = A * A * x2 - 2.f * A * Bc * c + Bc * Bc * y2l;
        const float den = fmaxf(1.f - 2.f * c + x2 * y2l, 1e-15f);
        float n = fsq(fmaxf(nn * frc(den * den), 1e-15f));
        n = fminf(n, MAXNORM);
        const float dd = __logf((1.f + n) * frc(1.f - n));   // 2*artanh(n)
        float dist = dd * dd;
        if (lane == ai) dist = 0.f;        // self-distance: ref < 1e-9 -> masked
        const float logit = (dist > 1e-9f) ? (-dist * (1.f / TAU)) : -1e30f;
        const float dp = bcast(dist, bi);
        const float lp = bcast(logit, bi);
        const float m  = wredmax(logit);
        const float se = wredsum(__expf(logit - m)) + __expf(lp - m);
        wacc += m + __logf(se) + dp * (1.f / TAU);
    }

    // ===== rank phase: 8 lanes/row (float8), 8 rows/wave, coalesced ========
    {
        const int sub = lane & 7;          // dim octet: dims sub*8..sub*8+7
        const int rw  = lane >> 3;         // row within wave
        float racc = 0.f;
        // rows per sweep = NWAVES*8 = 65536; 262144/65536 = 4 iterations
        for (int row = gw * 8 + rw; row < BROWS; row += NWAVES * 8) {
            const int* t = tri + (long)row * 10;
            const int2 t01 = *reinterpret_cast<const int2*>(t);
            const int2 t23 = *reinterpret_cast<const int2*>(t + 2);
            const int2 t45 = *reinterpret_cast<const int2*>(t + 4);
            const int2 t67 = *reinterpret_cast<const int2*>(t + 6);
            const int2 t89 = *reinterpret_cast<const int2*>(t + 8);
            const int nidx[NUM_NEG] = {t23.x, t23.y, t45.x, t45.y,
                                       t67.x, t67.y, t89.x, t89.y};
            const float* up = emb + (long)t01.x * 64 + sub * 8;
            float4 ua = *reinterpret_cast<const float4*>(up);
            const float4 ub = *reinterpret_cast<const float4*>(up + 4);
            const float* pp = emb + (long)t01.y * 64 + sub * 8;
            const float4 pa = *reinterpret_cast<const float4*>(pp);
            const float4 pb = *reinterpret_cast<const float4*>(pp + 4);
            const float u0 = ua.x;          // dim0 (valid on sub==0 only)
            if (sub == 0) ua.x = -ua.x;     // fold lorentz sign into u
            float dp = dot4(ua, pa) + dot4(ub, pb);
            dp += __shfl_xor(dp, 1); dp += __shfl_xor(dp, 2); dp += __shfl_xor(dp, 4);
            const float dpos  = acosh_fast(-dp);
            const float ps    = dpos * dpos;
            const float alpha = acosh_fast(u0);  // garbage on sub!=0 (discarded)
            float rs = 0.f;
            #pragma unroll
            for (int c = 0; c < 2; ++c) {
                float dn[4];
                #pragma unroll
                for (int k = 0; k < 4; ++k) {
                    const float* q = emb + (long)nidx[c * 4 + k] * 64 + sub * 8;
                    const float4 qa = *reinterpret_cast<const float4*>(q);
                    const float4 qb = *reinterpret_cast<const float4*>(q + 4);
                    dn[k] = dot4(ua, qa) + dot4(ub, qb);
                }
                #pragma unroll
                for (int k = 0; k < 4; ++k) {
                    float v = dn[k];
                    v += __shfl_xor(v, 1); v += __shfl_xor(v, 2); v += __shfl_xor(v, 4);
                    const float dneg = acosh_fast(-v);
                    rs += fmaxf((ps - dneg * dneg + MARGIN2) * alpha, 0.f);
                }
            }
            if (sub == 0) racc += rs;       // row-uniform; count once
        }
        wacc += wredsum(racc);
    }

    if (lane == 0) red4[wid] = wacc;
    __syncthreads();
    if (tid == 0) part[b] = red4[0] + red4[1] + red4[2] + red4[3];
}

__global__ __launch_bounds__(256) void final_reduce(
        const float* __restrict__ parts, int n, float* __restrict__ out) {
    __shared__ double red[256];
    double s = 0.0;
    for (int i = threadIdx.x; i < n; i += 256) s += (double)parts[i];
    red[threadIdx.x] = s;
    __syncthreads();
    for (int off = 128; off > 0; off >>= 1) {
        if (threadIdx.x < off) red[threadIdx.x] += red[threadIdx.x + off];
        __syncthreads();
    }
    if (threadIdx.x == 0) out[0] = (float)red[0];
}

} // namespace

extern "C" void kernel_launch(void* const* d_in, const int* in_sizes, int n_in,
                              void* d_out, int out_size, void* d_ws, size_t ws_size,
                              hipStream_t stream) {
    const float* emb    = (const float*)d_in[0];
    const float* vtg    = (const float*)d_in[1];
    const float* etag   = (const float*)d_in[2];
    const float* linw   = (const float*)d_in[3];
    const float* linb   = (const float*)d_in[4];
    const float* tw     = (const float*)d_in[5];
    const int*   tri    = (const int*)d_in[6];
    const int*   labels = (const int*)d_in[7];
    const int*   imp    = (const int*)d_in[8];
    float* parts = (float*)d_ws;

    fused_kernel<<<NBLK, 256, 0, stream>>>(emb, tri, vtg, etag, linw, linb,
                                           tw, labels, imp, parts);
    final_reduce<<<1, 256, 0, stream>>>(parts, NBLK, (float*)d_out);
}

// Round 9
// 83.638 us; speedup vs baseline: 2.1739x; 1.1455x over previous
//
#include <hip/hip_runtime.h>
#include <math.h>

namespace {

constexpr int NUM_NEG   = 8;
constexpr int BROWS     = 262144;
constexpr int NUM_ITEMS_C = 20000;
constexpr int M_IMP_C   = 2000;
constexpr float MARGIN1 = 0.1f;
constexpr float MARGIN2 = 0.1f;
constexpr float TAU     = 0.2f;
constexpr float EPS1    = 1e-7f;
constexpr float MAXNORM = 1.0f - 1e-5f;

// phase-serial fusion: every block does [cls -> cl -> rank]
constexpr int NBLK   = 4096;
constexpr int NWAVES = NBLK * 4;   // 16384

__device__ __forceinline__ float wredsum(float v) {
    v += __shfl_xor(v, 1);  v += __shfl_xor(v, 2);  v += __shfl_xor(v, 4);
    v += __shfl_xor(v, 8);  v += __shfl_xor(v, 16); v += __shfl_xor(v, 32);
    return v;
}
__device__ __forceinline__ float wredmax(float v) {
    v = fmaxf(v, __shfl_xor(v, 1));  v = fmaxf(v, __shfl_xor(v, 2));
    v = fmaxf(v, __shfl_xor(v, 4));  v = fmaxf(v, __shfl_xor(v, 8));
    v = fmaxf(v, __shfl_xor(v, 16)); v = fmaxf(v, __shfl_xor(v, 32));
    return v;
}
__device__ __forceinline__ float bcast(float v, int l) {
    return __int_as_float(__builtin_amdgcn_readlane(__float_as_int(v), l));
}
__device__ __forceinline__ float fsq(float x)  { return __builtin_amdgcn_sqrtf(x); }
__device__ __forceinline__ float frc(float x)  { return __builtin_amdgcn_rcpf(x); }
__device__ __forceinline__ float artanh_fast(float n) {
    n = fminf(n, MAXNORM);
    return 0.5f * __logf((1.f + n) * frc(1.f - n));
}
__device__ __forceinline__ float acosh_fast(float z) {
    z = fmaxf(z, 1.0f + EPS1);
    return __logf(z + fsq(fmaf(z, z, -1.0f)));
}
__device__ __forceinline__ float tanh_fast(float x) {
    const float t = __expf(2.f * x);
    return (t - 1.f) * frc(t + 1.f);
}
__device__ __forceinline__ float dot4(const float4& a, const float4& b) {
    return (a.x * b.x + a.y * b.y) + (a.z * b.z + a.w * b.w);
}

__global__ __launch_bounds__(256) void fused_kernel(
        const float* __restrict__ emb,  const int* __restrict__ tri,
        const float* __restrict__ vtg,  const float* __restrict__ etag,
        const float* __restrict__ linw, const float* __restrict__ linb,
        const float* __restrict__ tw,   const int* __restrict__ labels,
        const int* __restrict__ imp,    float* __restrict__ part) {
    __shared__ float SA[64 * 65];   // W^T -> BT -> TT (pitch 65)
    __shared__ float s64[64];
    __shared__ float red4[4];
    const int tid  = threadIdx.x;
    const int lane = tid & 63, wid = tid >> 6;
    const int b    = blockIdx.x;
    const int gw   = b * 4 + wid;          // global wave id, 0..16383
    float wacc = 0.f;

    // ================= cls phase: <=2 items per wave, batched ==============
    for (int i = tid; i < 4096; i += 256) {
        const int r = i >> 6, d = i & 63;
        SA[d * 65 + r] = linw[i];          // W transposed, pitch 65
    }
    __syncthreads();
    const float bias = linb[lane];
    const float y2b  = wredsum(bias * bias);
    const int i0 = gw, i1 = gw + NWAVES;   // i0 < 16384 < 20000 always valid
    const bool v1 = (i1 < NUM_ITEMS_C);

    float xv0 = vtg[(long)i0 * 64 + lane];
    float xv1 = v1 ? vtg[(long)i1 * 64 + lane] : 0.f;

    auto prep = [&](float& x) -> float {   // ball_projx; returns xn
        float n2 = wredsum(x * x);
        float n  = fsq(fmaxf(n2, 1e-15f));
        if (n > MAXNORM) {                 // wave-uniform
            x *= MAXNORM * frc(n);
            n2 = wredsum(x * x);
            n  = fsq(fmaxf(n2, 1e-15f));
        }
        return n;
    };
    const float xn0 = prep(xv0);
    const float xn1 = prep(xv1);

    // batched mobius_matvec: share the W ds_read across both items
    float ma0 = 0.f, ma1 = 0.f, mb0 = 0.f, mb1 = 0.f;
    #pragma unroll
    for (int d = 0; d < 64; d += 2) {
        const float w0 = SA[(d)     * 65 + lane];
        const float w1 = SA[(d + 1) * 65 + lane];
        ma0 = fmaf(bcast(xv0, d), w0, ma0);  ma1 = fmaf(bcast(xv0, d + 1), w1, ma1);
        mb0 = fmaf(bcast(xv1, d), w0, mb0);  mb1 = fmaf(bcast(xv1, d + 1), w1, mb1);
    }
    auto tail = [&](float mx, float xn) -> float {  // -> log-mapped a (lane d)
        const float mn  = fsq(fmaxf(wredsum(mx * mx), 1e-15f));
        const float g   = tanh_fast(mn * frc(xn) * artanh_fast(xn));
        const float h1  = g * frc(mn) * mx;
        const float x2h = wredsum(h1 * h1);
        const float xy  = wredsum(h1 * bias);
        const float A   = 1.f + 2.f * xy + y2b;
        const float Bc  = 1.f - x2h;
        const float den = fmaxf(1.f + 2.f * xy + x2h * y2b, 1e-15f);
        float hh = (A * h1 + Bc * bias) * frc(den);
        float hn = fsq(fmaxf(wredsum(hh * hh), 1e-15f));
        if (hn > MAXNORM) {                // ball_projx (wave-uniform)
            hh *= MAXNORM * frc(hn);
            hn = fsq(fmaxf(wredsum(hh * hh), 1e-15f));
        }
        return artanh_fast(hn) * frc(hn) * hh;     // ball_logmap0
    };
    const float av0 = tail(ma0 + ma1, xn0);
    const float av1 = tail(mb0 + mb1, xn1);
    __syncthreads();
    // rebuild LDS: BT = logmap0(emb_tag)^T, s64 = ||bt||^2
    {
        const int j = tid >> 2, p = tid & 3;
        float e[16]; float s2 = 0.f;
        #pragma unroll
        for (int m = 0; m < 16; ++m) { e[m] = etag[j * 64 + p * 16 + m]; s2 += e[m] * e[m]; }
        s2 += __shfl_xor(s2, 1); s2 += __shfl_xor(s2, 2);
        const float n  = fsq(fmaxf(s2, 1e-15f));
        const float sc = artanh_fast(n) * frc(n);
        #pragma unroll
        for (int m = 0; m < 16; ++m) SA[(p * 16 + m) * 65 + j] = sc * e[m];
        if (p == 0) s64[j] = sc * sc * s2;
    }
    __syncthreads();
    const float twl = tw[lane];
    const float b2l = s64[lane];
    // batched tag-distance dot: share the BT ds_read across both items
    float da0 = 0.f, da1 = 0.f, db0 = 0.f, db1 = 0.f;
    #pragma unroll
    for (int d = 0; d < 64; d += 2) {
        const float w0 = SA[(d)     * 65 + lane];
        const float w1 = SA[(d + 1) * 65 + lane];
        da0 = fmaf(bcast(av0, d), w0, da0);  da1 = fmaf(bcast(av0, d + 1), w1, da1);
        db0 = fmaf(bcast(av1, d), w0, db0);  db1 = fmaf(bcast(av1, d + 1), w1, db1);
    }
    auto hinge = [&](float a, float dot, int i) -> float {
        const float a2v  = wredsum(a * a);
        const float dist = fsq(fmaxf(a2v + b2l - 2.f * dot, 1e-12f));
        const float logp = __logf(dist) - twl;
        float s0 = 0.f, s1 = 0.f, s2 = 0.f, s3 = 0.f;
        #pragma unroll
        for (int k = 0; k < 64; k += 4) {
            s0 += fmaxf(logp - bcast(logp, k)     + MARGIN1, 0.f);
            s1 += fmaxf(logp - bcast(logp, k + 1) + MARGIN1, 0.f);
            s2 += fmaxf(logp - bcast(logp, k + 2) + MARGIN1, 0.f);
            s3 += fmaxf(logp - bcast(logp, k + 3) + MARGIN1, 0.f);
        }
        const float hs = (s0 + s1) + (s2 + s3);
        const float c  = (labels[(long)i * 64 + lane] > 0) ? hs : 0.f;
        return wredsum(c);
    };
    wacc += hinge(av0, da0 + da1, i0);
    if (v1) wacc += hinge(av1, db0 + db1, i1);
    __syncthreads();

    // ================= cl phase (<=1 pair per wave) ========================
    {   // rebuild LDS: TT = emb_tag^T (raw), s64 = ||tag||^2
        const int j = tid >> 2, p = tid & 3;
        float s2 = 0.f;
        #pragma unroll
        for (int m = 0; m < 16; ++m) {
            const float e = etag[j * 64 + p * 16 + m];
            s2 += e * e;
            SA[(p * 16 + m) * 65 + j] = e;
        }
        s2 += __shfl_xor(s2, 1); s2 += __shfl_xor(s2, 2);
        if (p == 0) s64[j] = s2;
    }
    __syncthreads();
    if (gw < M_IMP_C) {
        const int ai = imp[gw * 2];
        const int bi = imp[gw * 2 + 1];
        const float y2l = s64[lane];
        const float x2  = s64[ai];
        float c0 = 0.f, c1 = 0.f, c2 = 0.f, c3 = 0.f;
        #pragma unroll
        for (int d = 0; d < 64; d += 4) {
            c0 = fmaf(SA[(d)     * 65 + ai], SA[(d)     * 65 + lane], c0);
            c1 = fmaf(SA[(d + 1) * 65 + ai], SA[(d + 1) * 65 + lane], c1);
            c2 = fmaf(SA[(d + 2) * 65 + ai], SA[(d + 2) * 65 + lane], c2);
            c3 = fmaf(SA[(d + 3) * 65 + ai], SA[(d + 3) * 65 + lane], c3);
        }
        const float c   = (c0 + c1) + (c2 + c3);
        const float A   = 1.f - 2.f * c + y2l;
        const float Bc  = 1.f - x2;
        const float nn  = A * A * x2 - 2.f * A * Bc * c + Bc * Bc * y2l;
        const float den = fmaxf(1.f - 2.f * c + x2 * y2l, 1e-15f);
        float n = fsq(fmaxf(nn * frc(den * den), 1e-15f));
        n = fminf(n, MAXNORM);
        const float dd = __logf((1.f + n) * frc(1.f - n));   // 2*artanh(n)
        float dist = dd * dd;
        if (lane == ai) dist = 0.f;        // self-distance: ref < 1e-9 -> masked
        const float logit = (dist > 1e-9f) ? (-dist * (1.f / TAU)) : -1e30f;
        const float dp = bcast(dist, bi);
        const float lp = bcast(logit, bi);
        const float m  = wredmax(logit);
        const float se = wredsum(__expf(logit - m)) + __expf(lp - m);
        wacc += m + __logf(se) + dp * (1.f / TAU);
    }

    // == rank: 8 lanes/row (float8), 8 rows/wave, transpose-reduce over negs =
    {
        const int sub = lane & 7;          // dim octet: dims sub*8..sub*8+7
        const int rw  = lane >> 3;         // row within wave
        const bool o0 = sub & 1;
        const bool o1 = (sub >> 1) & 1;
        const bool o2 = (sub >> 2) & 1;
        float racc = 0.f;
        // rows/sweep = NWAVES*8 = 131072; 262144/131072 = 2 iterations exact
        #pragma unroll
        for (int it = 0; it < 2; ++it) {
            const int row = gw * 8 + rw + it * (NWAVES * 8);
            const int* t = tri + (long)row * 10;
            const int2 t01 = *reinterpret_cast<const int2*>(t);
            const int2 t23 = *reinterpret_cast<const int2*>(t + 2);
            const int2 t45 = *reinterpret_cast<const int2*>(t + 4);
            const int2 t67 = *reinterpret_cast<const int2*>(t + 6);
            const int2 t89 = *reinterpret_cast<const int2*>(t + 8);
            const int nidx[NUM_NEG] = {t23.x, t23.y, t45.x, t45.y,
                                       t67.x, t67.y, t89.x, t89.y};
            const float* up = emb + (long)t01.x * 64 + sub * 8;
            float4 ua = *reinterpret_cast<const float4*>(up);
            const float4 ub = *reinterpret_cast<const float4*>(up + 4);
            const float* pp = emb + (long)t01.y * 64 + sub * 8;
            const float4 pa = *reinterpret_cast<const float4*>(pp);
            const float4 pb = *reinterpret_cast<const float4*>(pp + 4);
            const float u0 = ua.x;          // dim0 (meaningful on sub==0)
            if (sub == 0) ua.x = -ua.x;     // fold lorentz sign into u
            float dp = dot4(ua, pa) + dot4(ub, pb);
            dp += __shfl_xor(dp, 1); dp += __shfl_xor(dp, 2); dp += __shfl_xor(dp, 4);
            const float dpos  = acosh_fast(-dp);
            const float ps    = dpos * dpos;
            const float alpha = acosh_fast(u0);  // used on sub==0 only
            // per-neg partial dots (this lane's 8 dims)
            float a[NUM_NEG];
            #pragma unroll
            for (int c = 0; c < 2; ++c) {
                #pragma unroll
                for (int k = 0; k < 4; ++k) {
                    const float* q = emb + (long)nidx[c * 4 + k] * 64 + sub * 8;
                    const float4 qa = *reinterpret_cast<const float4*>(q);
                    const float4 qb = *reinterpret_cast<const float4*>(q + 4);
                    a[c * 4 + k] = dot4(ua, qa) + dot4(ub, qb);
                }
            }
            // 3-stage transpose-reduce: lane sub ends with FULL dot of neg sub
            float s;
            s = o0 ? a[0] : a[1]; s = __shfl_xor(s, 1); const float b0 = (o0 ? a[1] : a[0]) + s;
            s = o0 ? a[2] : a[3]; s = __shfl_xor(s, 1); const float b1 = (o0 ? a[3] : a[2]) + s;
            s = o0 ? a[4] : a[5]; s = __shfl_xor(s, 1); const float b2 = (o0 ? a[5] : a[4]) + s;
            s = o0 ? a[6] : a[7]; s = __shfl_xor(s, 1); const float b3 = (o0 ? a[7] : a[6]) + s;
            s = o1 ? b0 : b1; s = __shfl_xor(s, 2); const float c0 = (o1 ? b1 : b0) + s;
            s = o1 ? b2 : b3; s = __shfl_xor(s, 2); const float c1 = (o1 ? b3 : b2) + s;
            s = o2 ? c0 : c1; s = __shfl_xor(s, 4); const float dn = (o2 ? c1 : c0) + s;
            // one acosh + one hinge per lane (covers all 8 negs of the row)
            const float dneg = acosh_fast(-dn);
            float hk = fmaxf(ps - dneg * dneg + MARGIN2, 0.f);
            hk += __shfl_xor(hk, 1); hk += __shfl_xor(hk, 2); hk += __shfl_xor(hk, 4);
            if (sub == 0) racc += alpha * hk;   // alpha >= 0 factored out
        }
        wacc += wredsum(racc);
    }

    if (lane == 0) red4[wid] = wacc;
    __syncthreads();
    if (tid == 0) part[b] = red4[0] + red4[1] + red4[2] + red4[3];
}

__global__ __launch_bounds__(256) void final_reduce(
        const float* __restrict__ parts, int n, float* __restrict__ out) {
    __shared__ double red[256];
    double s = 0.0;
    for (int i = threadIdx.x; i < n; i += 256) s += (double)parts[i];
    red[threadIdx.x] = s;
    __syncthreads();
    for (int off = 128; off > 0; off >>= 1) {
        if (threadIdx.x < off) red[threadIdx.x] += red[threadIdx.x + off];
        __syncthreads();
    }
    if (threadIdx.x == 0) out[0] = (float)red[0];
}

} // namespace

extern "C" void kernel_launch(void* const* d_in, const int* in_sizes, int n_in,
                              void* d_out, int out_size, void* d_ws, size_t ws_size,
                              hipStream_t stream) {
    const float* emb    = (const float*)d_in[0];
    const float* vtg    = (const float*)d_in[1];
    const float* etag   = (const float*)d_in[2];
    const float* linw   = (const float*)d_in[3];
    const float* linb   = (const float*)d_in[4];
    const float* tw     = (const float*)d_in[5];
    const int*   tri    = (const int*)d_in[6];
    const int*   labels = (const int*)d_in[7];
    const int*   imp    = (const int*)d_in[8];
    float* parts = (float*)d_ws;

    fused_kernel<<<NBLK, 256, 0, stream>>>(emb, tri, vtg, etag, linw, linb,
                                           tw, labels, imp, parts);
    final_reduce<<<1, 256, 0, stream>>>(parts, NBLK, (float*)d_out);
}